// Round 1
// baseline (471.940 us; speedup 1.0000x reference)
//
#include <hip/hip_runtime.h>
#include <hip/hip_bf16.h>
#include <math.h>

// Problem constants (B=1)
#define TT 512      // tokens = B*S
#define DD 1024     // model dim
#define FF 4096     // ffn dim
#define EE 8        // experts
#define RR 16       // lora rank
#define KKSEL 2     // top-k
#define SCALING 2.0f
#define EPSV 1e-6f

// ---------------- RMSNorm: x[T,D] -> t[T,D] ----------------
__global__ __launch_bounds__(256) void rmsnorm_k(const float* __restrict__ x,
                                                 const float* __restrict__ nw,
                                                 float* __restrict__ t) {
    int tok = blockIdx.x;
    const float* xr = x + (size_t)tok * DD;
    float ss = 0.f;
    for (int d = threadIdx.x; d < DD; d += 256) { float v = xr[d]; ss += v * v; }
    __shared__ float red[4];
    #pragma unroll
    for (int o = 32; o > 0; o >>= 1) ss += __shfl_down(ss, o);
    int wave = threadIdx.x >> 6, lane = threadIdx.x & 63;
    if (lane == 0) red[wave] = ss;
    __syncthreads();
    if (threadIdx.x == 0) {
        float s = red[0] + red[1] + red[2] + red[3];
        red[0] = rsqrtf(s * (1.0f / DD) + EPSV);
    }
    __syncthreads();
    float rs = red[0];
    for (int d = threadIdx.x; d < DD; d += 256)
        t[(size_t)tok * DD + d] = xr[d] * rs * nw[d];
}

// ---------------- Router: logits -> softmax -> top2 -> renorm ----------------
__global__ __launch_bounds__(64) void router_k(const float* __restrict__ t,
                                               const float* __restrict__ gw,
                                               float* __restrict__ topw,
                                               int* __restrict__ topi) {
    int tok = blockIdx.x;
    int lane = threadIdx.x;
    const float* tr = t + (size_t)tok * DD;
    float acc[EE];
    #pragma unroll
    for (int e = 0; e < EE; e++) acc[e] = 0.f;
    for (int d = lane; d < DD; d += 64) {
        float tv = tr[d];
        #pragma unroll
        for (int e = 0; e < EE; e++) acc[e] = fmaf(tv, gw[(size_t)e * DD + d], acc[e]);
    }
    #pragma unroll
    for (int e = 0; e < EE; e++) {
        #pragma unroll
        for (int o = 32; o > 0; o >>= 1) acc[e] += __shfl_down(acc[e], o);
    }
    if (lane == 0) {
        float m = acc[0];
        #pragma unroll
        for (int e = 1; e < EE; e++) m = fmaxf(m, acc[e]);
        float p[EE];
        #pragma unroll
        for (int e = 0; e < EE; e++) p[e] = expf(acc[e] - m);
        // top-2 (lowest index wins ties, matching lax.top_k)
        int i0 = 0; float v0 = p[0];
        for (int e = 1; e < EE; e++) if (p[e] > v0) { v0 = p[e]; i0 = e; }
        int i1 = -1; float v1 = -1.f;
        for (int e = 0; e < EE; e++) { if (e == i0) continue; if (p[e] > v1) { v1 = p[e]; i1 = e; } }
        float inv = 1.f / (v0 + v1);   // softmax denom cancels in renorm
        topi[tok * KKSEL + 0] = i0;
        topi[tok * KKSEL + 1] = i1;
        topw[tok * KKSEL + 0] = v0 * inv;
        topw[tok * KKSEL + 1] = v1 * inv;
    }
}

// ---------------- NT GEMM: C[m,n] = sum_k A[m,k]*B[n,k] ----------------
// 64x64 tile, BK=16, 256 threads, 4x4 per thread. blockIdx.z selects B0/C0 vs B1/C1.
__global__ __launch_bounds__(256) void gemm_nt_k(const float* __restrict__ A,
                                                 const float* __restrict__ B0,
                                                 const float* __restrict__ B1,
                                                 float* __restrict__ C0,
                                                 float* __restrict__ C1,
                                                 int M, int N, int Kd,
                                                 int lda, int ldb, int ldc) {
    const float* __restrict__ B = blockIdx.z ? B1 : B0;
    float* __restrict__ C = blockIdx.z ? C1 : C0;
    __shared__ float As[16][68];   // +4 pad: 2-way-max bank aliasing on writes
    __shared__ float Bs[16][68];
    int m0 = blockIdx.y * 64, n0 = blockIdx.x * 64;
    int tid = threadIdx.x;
    int tx = tid & 15, ty = tid >> 4;
    int lrow = tid >> 2;           // 0..63
    int lk = (tid & 3) << 2;       // 0,4,8,12
    float acc[4][4] = {};
    for (int k0 = 0; k0 < Kd; k0 += 16) {
        float4 av = *(const float4*)(A + (size_t)(m0 + lrow) * lda + k0 + lk);
        float4 bv = *(const float4*)(B + (size_t)(n0 + lrow) * ldb + k0 + lk);
        __syncthreads();
        As[lk + 0][lrow] = av.x; As[lk + 1][lrow] = av.y;
        As[lk + 2][lrow] = av.z; As[lk + 3][lrow] = av.w;
        Bs[lk + 0][lrow] = bv.x; Bs[lk + 1][lrow] = bv.y;
        Bs[lk + 2][lrow] = bv.z; Bs[lk + 3][lrow] = bv.w;
        __syncthreads();
        #pragma unroll
        for (int kk = 0; kk < 16; kk++) {
            float4 a4 = *(const float4*)&As[kk][ty << 2];
            float4 b4 = *(const float4*)&Bs[kk][tx << 2];
            float a[4] = {a4.x, a4.y, a4.z, a4.w};
            float b[4] = {b4.x, b4.y, b4.z, b4.w};
            #pragma unroll
            for (int i = 0; i < 4; i++)
                #pragma unroll
                for (int j = 0; j < 4; j++)
                    acc[i][j] = fmaf(a[i], b[j], acc[i][j]);
        }
    }
    #pragma unroll
    for (int i = 0; i < 4; i++) {
        float4 o = {acc[i][0], acc[i][1], acc[i][2], acc[i][3]};
        *(float4*)(C + (size_t)(m0 + ty * 4 + i) * ldc + n0 + tx * 4) = o;
    }
}

// ---------------- LoRA up + SwiGLU per (token,slot): act[slot,F] ----------------
__global__ __launch_bounds__(256) void lora_up_k(const float* __restrict__ t,
                                                 const float* __restrict__ a1,
                                                 const float* __restrict__ b1,
                                                 const float* __restrict__ a3,
                                                 const float* __restrict__ b3,
                                                 const float* __restrict__ base1,
                                                 const float* __restrict__ base3,
                                                 const int* __restrict__ topi,
                                                 float* __restrict__ act) {
    int slot = blockIdx.x;
    int tok = slot >> 1;
    int e = topi[slot];
    const float* tr = t + (size_t)tok * DD;
    __shared__ float s1[RR], s3[RR];
    int wave = threadIdx.x >> 6, lane = threadIdx.x & 63;
    #pragma unroll
    for (int rr = 0; rr < 4; rr++) {
        int r = wave * 4 + rr;
        const float* a1p = a1 + ((size_t)e * RR + r) * DD;
        const float* a3p = a3 + ((size_t)e * RR + r) * DD;
        float c1 = 0.f, c3 = 0.f;
        for (int d = lane; d < DD; d += 64) {
            float tv = tr[d];
            c1 = fmaf(tv, a1p[d], c1);
            c3 = fmaf(tv, a3p[d], c3);
        }
        #pragma unroll
        for (int o = 32; o > 0; o >>= 1) { c1 += __shfl_down(c1, o); c3 += __shfl_down(c3, o); }
        if (lane == 0) { s1[r] = SCALING * c1; s3[r] = SCALING * c3; }
    }
    __syncthreads();
    for (int f = threadIdx.x; f < FF; f += 256) {
        const float* b1p = b1 + ((size_t)e * FF + f) * RR;
        const float* b3p = b3 + ((size_t)e * FF + f) * RR;
        float h1 = base1[(size_t)tok * FF + f];
        float h3 = base3[(size_t)tok * FF + f];
        #pragma unroll
        for (int r = 0; r < RR; r++) {
            h1 = fmaf(s1[r], b1p[r], h1);
            h3 = fmaf(s3[r], b3p[r], h3);
        }
        float sig = 1.f / (1.f + expf(-h1));
        act[(size_t)slot * FF + f] = h1 * sig * h3;   // silu(h1)*h3
    }
}

// ---------------- s2[slot,r] = SCALING * act[slot,:] . a2[e,r,:] ----------------
__global__ __launch_bounds__(256) void s2_k(const float* __restrict__ act,
                                            const float* __restrict__ a2,
                                            const int* __restrict__ topi,
                                            float* __restrict__ s2) {
    int slot = blockIdx.x;
    int e = topi[slot];
    const float* ar = act + (size_t)slot * FF;
    int wave = threadIdx.x >> 6, lane = threadIdx.x & 63;
    #pragma unroll
    for (int rr = 0; rr < 4; rr++) {
        int r = wave * 4 + rr;
        const float* a2p = a2 + ((size_t)e * RR + r) * FF;
        float c = 0.f;
        for (int f = lane; f < FF; f += 64) c = fmaf(ar[f], a2p[f], c);
        #pragma unroll
        for (int o = 32; o > 0; o >>= 1) c += __shfl_down(c, o);
        if (lane == 0) s2[slot * RR + r] = SCALING * c;
    }
}

// ---------------- combine: out[t,d] = sum_k w_k * (down[slot,d] + s2.b2[e,d,:]) ----------------
__global__ __launch_bounds__(256) void combine_k(const float* __restrict__ down,
                                                 const float* __restrict__ s2,
                                                 const float* __restrict__ b2,
                                                 const float* __restrict__ topw,
                                                 const int* __restrict__ topi,
                                                 float* __restrict__ out) {
    int tok = blockIdx.x;
    for (int d = threadIdx.x; d < DD; d += 256) {
        float o = 0.f;
        #pragma unroll
        for (int k = 0; k < KKSEL; k++) {
            int slot = tok * KKSEL + k;
            int e = topi[slot];
            float w = topw[slot];
            float v = down[(size_t)slot * DD + d];
            const float* b2p = b2 + ((size_t)e * DD + d) * RR;
            const float* s2p = s2 + slot * RR;
            float l = 0.f;
            #pragma unroll
            for (int r = 0; r < RR; r++) l = fmaf(s2p[r], b2p[r], l);
            o += w * (v + l);
        }
        out[(size_t)tok * DD + d] = o;
    }
}

extern "C" void kernel_launch(void* const* d_in, const int* in_sizes, int n_in,
                              void* d_out, int out_size, void* d_ws, size_t ws_size,
                              hipStream_t stream) {
    const float* x  = (const float*)d_in[0];
    const float* nw = (const float*)d_in[1];
    const float* w1 = (const float*)d_in[2];
    const float* w3 = (const float*)d_in[3];
    const float* w2 = (const float*)d_in[4];
    const float* gw = (const float*)d_in[5];
    const float* a1 = (const float*)d_in[6];
    const float* b1 = (const float*)d_in[7];
    const float* a3 = (const float*)d_in[8];
    const float* b3 = (const float*)d_in[9];
    const float* a2 = (const float*)d_in[10];
    const float* b2 = (const float*)d_in[11];
    float* out = (float*)d_out;

    // workspace layout (~38 MB)
    float* t     = (float*)d_ws;
    float* base1 = t + (size_t)TT * DD;
    float* base3 = base1 + (size_t)TT * FF;
    float* act   = base3 + (size_t)TT * FF;
    float* down  = act + (size_t)TT * KKSEL * FF;
    float* s2    = down + (size_t)TT * KKSEL * DD;
    float* topw  = s2 + (size_t)TT * KKSEL * RR;
    int*   topi  = (int*)(topw + TT * KKSEL);

    rmsnorm_k<<<TT, 256, 0, stream>>>(x, nw, t);
    router_k<<<TT, 64, 0, stream>>>(t, gw, topw, topi);
    // base1 = t @ w1^T, base3 = t @ w3^T  (z selects w1/w3)
    gemm_nt_k<<<dim3(FF / 64, TT / 64, 2), 256, 0, stream>>>(
        t, w1, w3, base1, base3, TT, FF, DD, DD, DD, FF);
    lora_up_k<<<TT * KKSEL, 256, 0, stream>>>(t, a1, b1, a3, b3, base1, base3, topi, act);
    s2_k<<<TT * KKSEL, 256, 0, stream>>>(act, a2, topi, s2);
    // down[slot,d] = act[slot,:] @ w2[d,:]
    gemm_nt_k<<<dim3(DD / 64, (TT * KKSEL) / 64, 1), 256, 0, stream>>>(
        act, w2, w2, down, down, TT * KKSEL, DD, FF, FF, FF, DD);
    combine_k<<<TT, 256, 0, stream>>>(down, s2, b2, topw, topi, out);
}

// Round 2
// 243.601 us; speedup vs baseline: 1.9373x; 1.9373x over previous
//
#include <hip/hip_runtime.h>
#include <hip/hip_bf16.h>
#include <math.h>

// Problem constants (B=1)
#define TT 512      // tokens = B*S
#define DD 1024     // model dim
#define FF 4096     // ffn dim
#define EE 8        // experts
#define RR 16       // lora rank
#define KKSEL 2     // top-k
#define SCALING 2.0f
#define EPSV 1e-6f

typedef unsigned short u16;
typedef short bhalf8 __attribute__((ext_vector_type(8)));
typedef float floatx4 __attribute__((ext_vector_type(4)));

__device__ __forceinline__ u16 f2b(float f) {
    unsigned x = __builtin_bit_cast(unsigned, f);
    unsigned r = (x + 0x7fffu + ((x >> 16) & 1u)) >> 16;
    return (u16)r;
}

__device__ __forceinline__ void gl_lds16(const void* g, void* l) {
    __builtin_amdgcn_global_load_lds(
        (const __attribute__((address_space(1))) void*)g,
        (__attribute__((address_space(3))) void*)l, 16, 0, 0);
}

// ---------------- fp32 -> bf16 convert ----------------
__global__ __launch_bounds__(256) void f2b_k(const float* __restrict__ in,
                                             u16* __restrict__ out, int n) {
    int i = (blockIdx.x * 256 + threadIdx.x) * 4;
    int stride = gridDim.x * 256 * 4;
    for (; i < n; i += stride) {
        float4 v = *(const float4*)(in + i);
        ushort4 o = { f2b(v.x), f2b(v.y), f2b(v.z), f2b(v.w) };
        *(ushort4*)(out + i) = o;
    }
}

// ---------------- RMSNorm: x[T,D] -> t fp32 + bf16 ----------------
__global__ __launch_bounds__(256) void rmsnorm_k(const float* __restrict__ x,
                                                 const float* __restrict__ nw,
                                                 float* __restrict__ t,
                                                 u16* __restrict__ tb) {
    int tok = blockIdx.x;
    const float* xr = x + (size_t)tok * DD;
    float ss = 0.f;
    for (int d = threadIdx.x; d < DD; d += 256) { float v = xr[d]; ss += v * v; }
    __shared__ float red[4];
    #pragma unroll
    for (int o = 32; o > 0; o >>= 1) ss += __shfl_down(ss, o);
    int wave = threadIdx.x >> 6, lane = threadIdx.x & 63;
    if (lane == 0) red[wave] = ss;
    __syncthreads();
    if (threadIdx.x == 0) {
        float s = red[0] + red[1] + red[2] + red[3];
        red[0] = rsqrtf(s * (1.0f / DD) + EPSV);
    }
    __syncthreads();
    float rs = red[0];
    for (int d = threadIdx.x; d < DD; d += 256) {
        float v = xr[d] * rs * nw[d];
        t[(size_t)tok * DD + d] = v;
        tb[(size_t)tok * DD + d] = f2b(v);
    }
}

// ---------------- Router ----------------
__global__ __launch_bounds__(64) void router_k(const float* __restrict__ t,
                                               const float* __restrict__ gw,
                                               float* __restrict__ topw,
                                               int* __restrict__ topi) {
    int tok = blockIdx.x;
    int lane = threadIdx.x;
    const float* tr = t + (size_t)tok * DD;
    float acc[EE];
    #pragma unroll
    for (int e = 0; e < EE; e++) acc[e] = 0.f;
    for (int d = lane; d < DD; d += 64) {
        float tv = tr[d];
        #pragma unroll
        for (int e = 0; e < EE; e++) acc[e] = fmaf(tv, gw[(size_t)e * DD + d], acc[e]);
    }
    #pragma unroll
    for (int e = 0; e < EE; e++) {
        #pragma unroll
        for (int o = 32; o > 0; o >>= 1) acc[e] += __shfl_down(acc[e], o);
    }
    if (lane == 0) {
        float m = acc[0];
        #pragma unroll
        for (int e = 1; e < EE; e++) m = fmaxf(m, acc[e]);
        float p[EE];
        #pragma unroll
        for (int e = 0; e < EE; e++) p[e] = expf(acc[e] - m);
        int i0 = 0; float v0 = p[0];
        for (int e = 1; e < EE; e++) if (p[e] > v0) { v0 = p[e]; i0 = e; }
        int i1 = -1; float v1 = -1.f;
        for (int e = 0; e < EE; e++) { if (e == i0) continue; if (p[e] > v1) { v1 = p[e]; i1 = e; } }
        float inv = 1.f / (v0 + v1);
        topi[tok * KKSEL + 0] = i0;
        topi[tok * KKSEL + 1] = i1;
        topw[tok * KKSEL + 0] = v0 * inv;
        topw[tok * KKSEL + 1] = v1 * inv;
    }
}

// ---------------- bf16 MFMA NT GEMM (m97 structure) ----------------
// C[m,n] = sum_k A[m,k] * B[n,k]; A[M,K], B[N,K] bf16 row-major (ld=K), C fp32 (ld=N).
// 128x128 tile, BK=32, 256 threads = 4 waves (2x2), 4x4 fragments of 16x16x32 per wave.
// mode 0: z in {0,1} selects (B0->C0)/(B1->C1), full K.
// mode 1: split-K over 4 chunks: B0 -> C0 + z*M*N, k in [z*K/4, (z+1)*K/4).
__global__ __launch_bounds__(256) void gemm_bf16_k(const u16* __restrict__ A,
                                                   const u16* __restrict__ B0,
                                                   const u16* __restrict__ B1,
                                                   float* __restrict__ C0,
                                                   float* __restrict__ C1,
                                                   int M, int N, int K, int mode) {
    __shared__ u16 As[128 * 32];
    __shared__ u16 Bs[128 * 32];
    int tid = threadIdx.x;
    int w = tid >> 6, lane = tid & 63;
    int wr = w >> 1, wc = w & 1;
    int lr = lane & 15, ks = lane >> 4;
    int z = blockIdx.z;
    const u16* B = B0; float* C = C0;
    int k0s = 0, k0e = K;
    if (mode == 0) {
        if (z) { B = B1; C = C1; }
    } else {
        C = C0 + (size_t)z * M * N;
        int kc = K >> 2; k0s = z * kc; k0e = k0s + kc;
    }
    int m0 = blockIdx.y * 128, n0 = blockIdx.x * 128;

    // staging geometry: tile = 128 rows x 64 bytes; thread covers 16B at flat=tid*16
    int flat = tid * 16;
    int row = flat >> 6;       // 0..63
    int inb = flat & 63;
    size_t rb = (size_t)K * 2; // row bytes
    const char* Ab  = (const char*)A + (size_t)(m0 + row) * rb + inb;
    const char* Ab2 = Ab + 64 * rb;
    const char* Bb  = (const char*)B + (size_t)(n0 + row) * rb + inb;
    const char* Bb2 = Bb + 64 * rb;
    u16* AsW = As + w * 512;   // wave-uniform LDS dest (issue 0)
    u16* BsW = Bs + w * 512;

    floatx4 zero4 = {0.f, 0.f, 0.f, 0.f};
    floatx4 acc[4][4];
    #pragma unroll
    for (int i = 0; i < 4; i++)
        #pragma unroll
        for (int j = 0; j < 4; j++) acc[i][j] = zero4;

    for (int k0 = k0s; k0 < k0e; k0 += 32) {
        size_t kb = (size_t)k0 * 2;
        gl_lds16(Ab + kb, AsW);
        gl_lds16(Ab2 + kb, AsW + 2048);
        gl_lds16(Bb + kb, BsW);
        gl_lds16(Bb2 + kb, BsW + 2048);
        __syncthreads();
        bhalf8 af[4], bg[4];
        #pragma unroll
        for (int i = 0; i < 4; i++) {
            af[i] = *(const bhalf8*)&As[(wr * 64 + i * 16 + lr) * 32 + ks * 8];
            bg[i] = *(const bhalf8*)&Bs[(wc * 64 + i * 16 + lr) * 32 + ks * 8];
        }
        #pragma unroll
        for (int i = 0; i < 4; i++)
            #pragma unroll
            for (int j = 0; j < 4; j++)
                acc[i][j] = __builtin_amdgcn_mfma_f32_16x16x32_bf16(af[i], bg[j], acc[i][j], 0, 0, 0);
        __syncthreads();
    }

    int crow = (lane >> 4) * 4;
    #pragma unroll
    for (int i = 0; i < 4; i++) {
        #pragma unroll
        for (int j = 0; j < 4; j++) {
            float* Cp = C + (size_t)(m0 + wr * 64 + i * 16 + crow) * N + (n0 + wc * 64 + j * 16 + lr);
            Cp[0]            = acc[i][j][0];
            Cp[(size_t)N]    = acc[i][j][1];
            Cp[(size_t)2*N]  = acc[i][j][2];
            Cp[(size_t)3*N]  = acc[i][j][3];
        }
    }
}

// ---------------- LoRA up + SwiGLU per (token,slot) ----------------
__global__ __launch_bounds__(256) void lora_up_k(const float* __restrict__ t,
                                                 const float* __restrict__ a1,
                                                 const float* __restrict__ b1,
                                                 const float* __restrict__ a3,
                                                 const float* __restrict__ b3,
                                                 const float* __restrict__ base1,
                                                 const float* __restrict__ base3,
                                                 const int* __restrict__ topi,
                                                 float* __restrict__ act,
                                                 u16* __restrict__ actb) {
    int slot = blockIdx.x;
    int tok = slot >> 1;
    int e = topi[slot];
    const float* tr = t + (size_t)tok * DD;
    __shared__ float s1[RR], s3[RR];
    int wave = threadIdx.x >> 6, lane = threadIdx.x & 63;
    #pragma unroll
    for (int rr = 0; rr < 4; rr++) {
        int r = wave * 4 + rr;
        const float* a1p = a1 + ((size_t)e * RR + r) * DD;
        const float* a3p = a3 + ((size_t)e * RR + r) * DD;
        float c1 = 0.f, c3 = 0.f;
        for (int d = lane; d < DD; d += 64) {
            float tv = tr[d];
            c1 = fmaf(tv, a1p[d], c1);
            c3 = fmaf(tv, a3p[d], c3);
        }
        #pragma unroll
        for (int o = 32; o > 0; o >>= 1) { c1 += __shfl_down(c1, o); c3 += __shfl_down(c3, o); }
        if (lane == 0) { s1[r] = SCALING * c1; s3[r] = SCALING * c3; }
    }
    __syncthreads();
    for (int f = threadIdx.x; f < FF; f += 256) {
        const float* b1p = b1 + ((size_t)e * FF + f) * RR;
        const float* b3p = b3 + ((size_t)e * FF + f) * RR;
        float h1 = base1[(size_t)tok * FF + f];
        float h3 = base3[(size_t)tok * FF + f];
        #pragma unroll
        for (int r = 0; r < RR; r++) {
            h1 = fmaf(s1[r], b1p[r], h1);
            h3 = fmaf(s3[r], b3p[r], h3);
        }
        float sig = 1.f / (1.f + expf(-h1));
        float v = h1 * sig * h3;
        act[(size_t)slot * FF + f] = v;
        actb[(size_t)slot * FF + f] = f2b(v);
    }
}

// ---------------- s2[slot,r] = SCALING * act[slot,:] . a2[e,r,:] ----------------
__global__ __launch_bounds__(256) void s2_k(const float* __restrict__ act,
                                            const float* __restrict__ a2,
                                            const int* __restrict__ topi,
                                            float* __restrict__ s2) {
    int slot = blockIdx.x;
    int e = topi[slot];
    const float* ar = act + (size_t)slot * FF;
    int wave = threadIdx.x >> 6, lane = threadIdx.x & 63;
    #pragma unroll
    for (int rr = 0; rr < 4; rr++) {
        int r = wave * 4 + rr;
        const float* a2p = a2 + ((size_t)e * RR + r) * FF;
        float c = 0.f;
        for (int f = lane; f < FF; f += 64) c = fmaf(ar[f], a2p[f], c);
        #pragma unroll
        for (int o = 32; o > 0; o >>= 1) c += __shfl_down(c, o);
        if (lane == 0) s2[slot * RR + r] = SCALING * c;
    }
}

// ---------------- combine: sum split-K partials + LoRA-down + expert weights ----------------
__global__ __launch_bounds__(256) void combine_k(const float* __restrict__ downP,
                                                 const float* __restrict__ s2,
                                                 const float* __restrict__ b2,
                                                 const float* __restrict__ topw,
                                                 const int* __restrict__ topi,
                                                 float* __restrict__ out) {
    int tok = blockIdx.x;
    for (int d = threadIdx.x; d < DD; d += 256) {
        float o = 0.f;
        #pragma unroll
        for (int k = 0; k < KKSEL; k++) {
            int slot = tok * KKSEL + k;
            int e = topi[slot];
            float w = topw[slot];
            float v = 0.f;
            #pragma unroll
            for (int zz = 0; zz < 4; zz++)
                v += downP[(size_t)zz * (TT * KKSEL) * DD + (size_t)slot * DD + d];
            const float* b2p = b2 + ((size_t)e * DD + d) * RR;
            const float* s2p = s2 + slot * RR;
            float l = 0.f;
            #pragma unroll
            for (int r = 0; r < RR; r++) l = fmaf(s2p[r], b2p[r], l);
            o += w * (v + l);
        }
        out[(size_t)tok * DD + d] = o;
    }
}

extern "C" void kernel_launch(void* const* d_in, const int* in_sizes, int n_in,
                              void* d_out, int out_size, void* d_ws, size_t ws_size,
                              hipStream_t stream) {
    const float* x  = (const float*)d_in[0];
    const float* nw = (const float*)d_in[1];
    const float* w1 = (const float*)d_in[2];
    const float* w3 = (const float*)d_in[3];
    const float* w2 = (const float*)d_in[4];
    const float* gw = (const float*)d_in[5];
    const float* a1 = (const float*)d_in[6];
    const float* b1 = (const float*)d_in[7];
    const float* a3 = (const float*)d_in[8];
    const float* b3 = (const float*)d_in[9];
    const float* a2 = (const float*)d_in[10];
    const float* b2 = (const float*)d_in[11];
    float* out = (float*)d_out;

    // workspace layout (~87 MB), all chunks 16B-aligned
    float* t     = (float*)d_ws;                         // 512*1024 f32
    float* base1 = t + (size_t)TT * DD;                  // 512*4096
    float* base3 = base1 + (size_t)TT * FF;              // 512*4096
    float* act   = base3 + (size_t)TT * FF;              // 1024*4096
    float* downP = act + (size_t)TT * KKSEL * FF;        // 4 * 1024*1024
    float* s2    = downP + (size_t)4 * TT * KKSEL * DD;  // 1024*16
    float* topw  = s2 + (size_t)TT * KKSEL * RR;         // 1024
    int*   topi  = (int*)(topw + TT * KKSEL);            // 1024
    u16*   tb    = (u16*)(topi + TT * KKSEL);            // 512*1024 bf16
    u16*   w1b   = tb + (size_t)TT * DD;                 // 4096*1024
    u16*   w3b   = w1b + (size_t)FF * DD;
    u16*   w2b   = w3b + (size_t)FF * DD;
    u16*   actb  = w2b + (size_t)DD * FF;                // 1024*4096

    f2b_k<<<4096, 256, 0, stream>>>(w1, w1b, FF * DD);
    f2b_k<<<4096, 256, 0, stream>>>(w3, w3b, FF * DD);
    f2b_k<<<4096, 256, 0, stream>>>(w2, w2b, DD * FF);
    rmsnorm_k<<<TT, 256, 0, stream>>>(x, nw, t, tb);
    router_k<<<TT, 64, 0, stream>>>(t, gw, topw, topi);
    // base1 = t @ w1^T, base3 = t @ w3^T
    gemm_bf16_k<<<dim3(FF / 128, TT / 128, 2), 256, 0, stream>>>(
        tb, w1b, w3b, base1, base3, TT, FF, DD, 0);
    lora_up_k<<<TT * KKSEL, 256, 0, stream>>>(t, a1, b1, a3, b3, base1, base3, topi, act, actb);
    s2_k<<<TT * KKSEL, 256, 0, stream>>>(act, a2, topi, s2);
    // down[slot,d] = act[slot,:] @ w2[d,:], split-K=4
    gemm_bf16_k<<<dim3(DD / 128, (TT * KKSEL) / 128, 4), 256, 0, stream>>>(
        actb, w2b, w2b, downP, downP, TT * KKSEL, DD, FF, 1);
    combine_k<<<TT, 256, 0, stream>>>(downP, s2, b2, topw, topi, out);
}

// Round 3
// 160.493 us; speedup vs baseline: 2.9406x; 1.5178x over previous
//
#include <hip/hip_runtime.h>
#include <hip/hip_bf16.h>
#include <math.h>

// Problem constants (B=1)
#define TT 512      // tokens = B*S
#define DD 1024     // model dim
#define FF 4096     // ffn dim
#define EE 8        // experts
#define RR 16       // lora rank
#define KKSEL 2     // top-k
#define SCALING 2.0f
#define EPSV 1e-6f

typedef unsigned short u16;
typedef short bhalf8 __attribute__((ext_vector_type(8)));
typedef float floatx4 __attribute__((ext_vector_type(4)));

__device__ __forceinline__ u16 f2b(float f) {
    unsigned x = __builtin_bit_cast(unsigned, f);
    unsigned r = (x + 0x7fffu + ((x >> 16) & 1u)) >> 16;
    return (u16)r;
}
__device__ __forceinline__ float b2f(u16 b) {
    unsigned x = ((unsigned)b) << 16;
    return __builtin_bit_cast(float, x);
}

__device__ __forceinline__ void gl_lds16(const void* g, void* l) {
    __builtin_amdgcn_global_load_lds(
        (const __attribute__((address_space(1))) void*)g,
        (__attribute__((address_space(3))) void*)l, 16, 0, 0);
}

// ---------------- fp32 -> bf16 convert ----------------
__global__ __launch_bounds__(256) void f2b_k(const float* __restrict__ in,
                                             u16* __restrict__ out, int n) {
    int i = (blockIdx.x * 256 + threadIdx.x) * 4;
    int stride = gridDim.x * 256 * 4;
    for (; i < n; i += stride) {
        float4 v = *(const float4*)(in + i);
        ushort4 o = { f2b(v.x), f2b(v.y), f2b(v.z), f2b(v.w) };
        *(ushort4*)(out + i) = o;
    }
}

// ---------------- RMSNorm: x[T,D] -> t fp32 + bf16 ----------------
__global__ __launch_bounds__(256) void rmsnorm_k(const float* __restrict__ x,
                                                 const float* __restrict__ nw,
                                                 float* __restrict__ t,
                                                 u16* __restrict__ tb) {
    int tok = blockIdx.x;
    const float* xr = x + (size_t)tok * DD;
    float ss = 0.f;
    for (int d = threadIdx.x; d < DD; d += 256) { float v = xr[d]; ss += v * v; }
    __shared__ float red[4];
    #pragma unroll
    for (int o = 32; o > 0; o >>= 1) ss += __shfl_down(ss, o);
    int wave = threadIdx.x >> 6, lane = threadIdx.x & 63;
    if (lane == 0) red[wave] = ss;
    __syncthreads();
    if (threadIdx.x == 0) {
        float s = red[0] + red[1] + red[2] + red[3];
        red[0] = rsqrtf(s * (1.0f / DD) + EPSV);
    }
    __syncthreads();
    float rs = red[0];
    for (int d = threadIdx.x; d < DD; d += 256) {
        float v = xr[d] * rs * nw[d];
        t[(size_t)tok * DD + d] = v;
        tb[(size_t)tok * DD + d] = f2b(v);
    }
}

// ---------------- Router ----------------
__global__ __launch_bounds__(64) void router_k(const float* __restrict__ t,
                                               const float* __restrict__ gw,
                                               float* __restrict__ topw,
                                               int* __restrict__ topi) {
    int tok = blockIdx.x;
    int lane = threadIdx.x;
    const float* tr = t + (size_t)tok * DD;
    float acc[EE];
    #pragma unroll
    for (int e = 0; e < EE; e++) acc[e] = 0.f;
    for (int d = lane; d < DD; d += 64) {
        float tv = tr[d];
        #pragma unroll
        for (int e = 0; e < EE; e++) acc[e] = fmaf(tv, gw[(size_t)e * DD + d], acc[e]);
    }
    #pragma unroll
    for (int e = 0; e < EE; e++) {
        #pragma unroll
        for (int o = 32; o > 0; o >>= 1) acc[e] += __shfl_down(acc[e], o);
    }
    if (lane == 0) {
        float m = acc[0];
        #pragma unroll
        for (int e = 1; e < EE; e++) m = fmaxf(m, acc[e]);
        float p[EE];
        #pragma unroll
        for (int e = 0; e < EE; e++) p[e] = expf(acc[e] - m);
        int i0 = 0; float v0 = p[0];
        for (int e = 1; e < EE; e++) if (p[e] > v0) { v0 = p[e]; i0 = e; }
        int i1 = -1; float v1 = -1.f;
        for (int e = 0; e < EE; e++) { if (e == i0) continue; if (p[e] > v1) { v1 = p[e]; i1 = e; } }
        float inv = 1.f / (v0 + v1);
        topi[tok * KKSEL + 0] = i0;
        topi[tok * KKSEL + 1] = i1;
        topw[tok * KKSEL + 0] = v0 * inv;
        topw[tok * KKSEL + 1] = v1 * inv;
    }
}

// ---------------- s1/s3: s[slot,r] = SCALING * t[tok,:] . a[e,r,:] ----------------
// grid = TT blocks; wave w -> (slot-half = w>>1, tensor = w&1)
__global__ __launch_bounds__(256) void s13_k(const float* __restrict__ t,
                                             const float* __restrict__ a1,
                                             const float* __restrict__ a3,
                                             const int* __restrict__ topi,
                                             float* __restrict__ s1,
                                             float* __restrict__ s3) {
    int tok = blockIdx.x;
    int w = threadIdx.x >> 6, lane = threadIdx.x & 63;
    int slot = tok * 2 + (w >> 1);
    int e = topi[slot];
    const float* ap = (w & 1) ? a3 : a1;
    float* sp = (w & 1) ? s3 : s1;
    const float* tr = t + (size_t)tok * DD;
    float tv[16];
    #pragma unroll
    for (int i = 0; i < 16; i++) tv[i] = tr[lane + 64 * i];
    const float* ab = ap + (size_t)e * RR * DD;
    #pragma unroll
    for (int r = 0; r < RR; r++) {
        const float* ar = ab + (size_t)r * DD;
        float c = 0.f;
        #pragma unroll
        for (int i = 0; i < 16; i++) c = fmaf(tv[i], ar[lane + 64 * i], c);
        #pragma unroll
        for (int o = 32; o > 0; o >>= 1) c += __shfl_down(c, o);
        if (lane == 0) sp[slot * RR + r] = SCALING * c;
    }
}

// ---------------- fused: base GEMMs (t@w1^T, t@w3^T) + LoRA-up + SwiGLU -> actb bf16 ----
// Tile: 128 tokens x 64 f cols, BK=32. 256 threads = 4 waves (2x2), wave tile 64x32.
__global__ __launch_bounds__(256) void gemm1_fused_k(const u16* __restrict__ tb,
                                                     const u16* __restrict__ w1b,
                                                     const u16* __restrict__ w3b,
                                                     const float* __restrict__ b1,
                                                     const float* __restrict__ b3,
                                                     const float* __restrict__ s1,
                                                     const float* __restrict__ s3,
                                                     const int* __restrict__ topi,
                                                     u16* __restrict__ actb) {
    __shared__ u16 As[128 * 32];
    __shared__ u16 B1s[64 * 32];
    __shared__ u16 B3s[64 * 32];
    __shared__ float sL[2][256 * 16];   // [tensor][slot_local*16+r], 32KB
    __shared__ int eL[256];
    int tid = threadIdx.x;
    int w = tid >> 6, lane = tid & 63;
    int wr = w >> 1, wc = w & 1;
    int lr = lane & 15, ks = lane >> 4;
    int m0 = blockIdx.y * 128, n0 = blockIdx.x * 64;

    // preload per-slot scalars (visible after first __syncthreads)
    eL[tid] = topi[m0 * 2 + tid];
    for (int i = tid * 4; i < 256 * 16; i += 1024) {
        *(float4*)&sL[0][i] = *(const float4*)&s1[(size_t)m0 * 2 * RR + i];
        *(float4*)&sL[1][i] = *(const float4*)&s3[(size_t)m0 * 2 * RR + i];
    }

    int flat = tid * 16;
    int row = flat >> 6;     // 0..63
    int inb = flat & 63;
    const size_t rb = (size_t)DD * 2;  // K = DD, row bytes
    const char* Ap  = (const char*)tb  + (size_t)(m0 + row) * rb + inb;
    const char* Ap2 = Ap + 64 * rb;
    const char* B1p = (const char*)w1b + (size_t)(n0 + row) * rb + inb;
    const char* B3p = (const char*)w3b + (size_t)(n0 + row) * rb + inb;
    u16* AsW = As + w * 512;
    u16* B1W = B1s + w * 512;
    u16* B3W = B3s + w * 512;

    floatx4 zero4 = {0.f, 0.f, 0.f, 0.f};
    floatx4 acc1[4][2], acc3[4][2];
    #pragma unroll
    for (int i = 0; i < 4; i++)
        #pragma unroll
        for (int j = 0; j < 2; j++) { acc1[i][j] = zero4; acc3[i][j] = zero4; }

    for (int k0 = 0; k0 < DD; k0 += 32) {
        size_t kb = (size_t)k0 * 2;
        gl_lds16(Ap + kb, AsW);
        gl_lds16(Ap2 + kb, AsW + 2048);
        gl_lds16(B1p + kb, B1W);
        gl_lds16(B3p + kb, B3W);
        __syncthreads();
        bhalf8 af[4], bg1[2], bg3[2];
        #pragma unroll
        for (int i = 0; i < 4; i++)
            af[i] = *(const bhalf8*)&As[(wr * 64 + i * 16 + lr) * 32 + ks * 8];
        #pragma unroll
        for (int j = 0; j < 2; j++) {
            bg1[j] = *(const bhalf8*)&B1s[(wc * 32 + j * 16 + lr) * 32 + ks * 8];
            bg3[j] = *(const bhalf8*)&B3s[(wc * 32 + j * 16 + lr) * 32 + ks * 8];
        }
        #pragma unroll
        for (int i = 0; i < 4; i++)
            #pragma unroll
            for (int j = 0; j < 2; j++) {
                acc1[i][j] = __builtin_amdgcn_mfma_f32_16x16x32_bf16(af[i], bg1[j], acc1[i][j], 0, 0, 0);
                acc3[i][j] = __builtin_amdgcn_mfma_f32_16x16x32_bf16(af[i], bg3[j], acc3[i][j], 0, 0, 0);
            }
        __syncthreads();
    }

    // epilogue: h = base + s . b ; act = silu(h1)*h3 -> bf16
    int crow = (lane >> 4) * 4;
    #pragma unroll
    for (int j = 0; j < 2; j++) {
        int col = n0 + wc * 32 + j * 16 + lr;
        #pragma unroll
        for (int i = 0; i < 4; i++) {
            #pragma unroll
            for (int m = 0; m < 4; m++) {
                int rowl = wr * 64 + i * 16 + crow + m;
                float hb1 = acc1[i][j][m], hb3 = acc3[i][j][m];
                #pragma unroll
                for (int k = 0; k < KKSEL; k++) {
                    int sl = rowl * 2 + k;
                    int e = eL[sl];
                    const float* bp1 = b1 + ((size_t)e * FF + col) * RR;
                    const float* bp3 = b3 + ((size_t)e * FF + col) * RR;
                    const float* sp1 = &sL[0][sl * 16];
                    const float* sp3 = &sL[1][sl * 16];
                    float d1 = 0.f, d3 = 0.f;
                    #pragma unroll
                    for (int r = 0; r < RR; r++) {
                        d1 = fmaf(sp1[r], bp1[r], d1);
                        d3 = fmaf(sp3[r], bp3[r], d3);
                    }
                    float h1 = hb1 + d1, h3 = hb3 + d3;
                    float sig = 1.f / (1.f + expf(-h1));
                    actb[(size_t)(m0 * 2 + sl) * FF + col] = f2b(h1 * sig * h3);
                }
            }
        }
    }
}

// ---------------- s2[slot,r] = SCALING * act[slot,:] . a2[e,r,:]  (bf16 act) --------
__global__ __launch_bounds__(256) void s2_k(const u16* __restrict__ actb,
                                            const float* __restrict__ a2,
                                            const int* __restrict__ topi,
                                            float* __restrict__ s2) {
    int slot = blockIdx.x;
    int e = topi[slot];
    const u16* ar = actb + (size_t)slot * FF;
    int wave = threadIdx.x >> 6, lane = threadIdx.x & 63;
    // preload act row: lane covers f = lane*4 + 256*i, i<16 (ushort4 each)
    float av[64];
    #pragma unroll
    for (int i = 0; i < 16; i++) {
        ushort4 u = *(const ushort4*)(ar + lane * 4 + 256 * i);
        av[i * 4 + 0] = b2f(u.x); av[i * 4 + 1] = b2f(u.y);
        av[i * 4 + 2] = b2f(u.z); av[i * 4 + 3] = b2f(u.w);
    }
    #pragma unroll
    for (int rr = 0; rr < 4; rr++) {
        int r = wave * 4 + rr;
        const float* a2p = a2 + ((size_t)e * RR + r) * FF;
        float c = 0.f;
        #pragma unroll
        for (int i = 0; i < 16; i++) {
            float4 w4 = *(const float4*)(a2p + lane * 4 + 256 * i);
            c = fmaf(av[i * 4 + 0], w4.x, c);
            c = fmaf(av[i * 4 + 1], w4.y, c);
            c = fmaf(av[i * 4 + 2], w4.z, c);
            c = fmaf(av[i * 4 + 3], w4.w, c);
        }
        #pragma unroll
        for (int o = 32; o > 0; o >>= 1) c += __shfl_down(c, o);
        if (lane == 0) s2[slot * RR + r] = SCALING * c;
    }
}

// ---------------- bf16 MFMA NT GEMM, split-K (down proj) ----------------
// C[m,n] = sum_k A[m,k]*B[n,k]; 128x128 tile, BK=32; z = split-K chunk of 4.
__global__ __launch_bounds__(256) void gemm_bf16_k(const u16* __restrict__ A,
                                                   const u16* __restrict__ B,
                                                   float* __restrict__ C0,
                                                   int M, int N, int K) {
    __shared__ u16 As[128 * 32];
    __shared__ u16 Bs[128 * 32];
    int tid = threadIdx.x;
    int w = tid >> 6, lane = tid & 63;
    int wr = w >> 1, wc = w & 1;
    int lr = lane & 15, ks = lane >> 4;
    int z = blockIdx.z;
    float* C = C0 + (size_t)z * M * N;
    int kc = K >> 2, k0s = z * kc, k0e = k0s + kc;
    int m0 = blockIdx.y * 128, n0 = blockIdx.x * 128;

    int flat = tid * 16;
    int row = flat >> 6;
    int inb = flat & 63;
    size_t rb = (size_t)K * 2;
    const char* Ab  = (const char*)A + (size_t)(m0 + row) * rb + inb;
    const char* Ab2 = Ab + 64 * rb;
    const char* Bb  = (const char*)B + (size_t)(n0 + row) * rb + inb;
    const char* Bb2 = Bb + 64 * rb;
    u16* AsW = As + w * 512;
    u16* BsW = Bs + w * 512;

    floatx4 zero4 = {0.f, 0.f, 0.f, 0.f};
    floatx4 acc[4][4];
    #pragma unroll
    for (int i = 0; i < 4; i++)
        #pragma unroll
        for (int j = 0; j < 4; j++) acc[i][j] = zero4;

    for (int k0 = k0s; k0 < k0e; k0 += 32) {
        size_t kb = (size_t)k0 * 2;
        gl_lds16(Ab + kb, AsW);
        gl_lds16(Ab2 + kb, AsW + 2048);
        gl_lds16(Bb + kb, BsW);
        gl_lds16(Bb2 + kb, BsW + 2048);
        __syncthreads();
        bhalf8 af[4], bg[4];
        #pragma unroll
        for (int i = 0; i < 4; i++) {
            af[i] = *(const bhalf8*)&As[(wr * 64 + i * 16 + lr) * 32 + ks * 8];
            bg[i] = *(const bhalf8*)&Bs[(wc * 64 + i * 16 + lr) * 32 + ks * 8];
        }
        #pragma unroll
        for (int i = 0; i < 4; i++)
            #pragma unroll
            for (int j = 0; j < 4; j++)
                acc[i][j] = __builtin_amdgcn_mfma_f32_16x16x32_bf16(af[i], bg[j], acc[i][j], 0, 0, 0);
        __syncthreads();
    }

    int crow = (lane >> 4) * 4;
    #pragma unroll
    for (int i = 0; i < 4; i++) {
        #pragma unroll
        for (int j = 0; j < 4; j++) {
            float* Cp = C + (size_t)(m0 + wr * 64 + i * 16 + crow) * N + (n0 + wc * 64 + j * 16 + lr);
            Cp[0]           = acc[i][j][0];
            Cp[(size_t)N]   = acc[i][j][1];
            Cp[(size_t)2*N] = acc[i][j][2];
            Cp[(size_t)3*N] = acc[i][j][3];
        }
    }
}

// ---------------- combine: split-K partials + LoRA-down + expert weights ----------------
__global__ __launch_bounds__(256) void combine_k(const float* __restrict__ downP,
                                                 const float* __restrict__ s2,
                                                 const float* __restrict__ b2,
                                                 const float* __restrict__ topw,
                                                 const int* __restrict__ topi,
                                                 float* __restrict__ out) {
    int tok = blockIdx.x;
    for (int d = threadIdx.x; d < DD; d += 256) {
        float o = 0.f;
        #pragma unroll
        for (int k = 0; k < KKSEL; k++) {
            int slot = tok * KKSEL + k;
            int e = topi[slot];
            float w = topw[slot];
            float v = 0.f;
            #pragma unroll
            for (int zz = 0; zz < 4; zz++)
                v += downP[(size_t)zz * (TT * KKSEL) * DD + (size_t)slot * DD + d];
            const float* b2p = b2 + ((size_t)e * DD + d) * RR;
            const float* s2p = s2 + slot * RR;
            float l = 0.f;
            #pragma unroll
            for (int r = 0; r < RR; r++) l = fmaf(s2p[r], b2p[r], l);
            o += w * (v + l);
        }
        out[(size_t)tok * DD + d] = o;
    }
}

extern "C" void kernel_launch(void* const* d_in, const int* in_sizes, int n_in,
                              void* d_out, int out_size, void* d_ws, size_t ws_size,
                              hipStream_t stream) {
    const float* x  = (const float*)d_in[0];
    const float* nw = (const float*)d_in[1];
    const float* w1 = (const float*)d_in[2];
    const float* w3 = (const float*)d_in[3];
    const float* w2 = (const float*)d_in[4];
    const float* gw = (const float*)d_in[5];
    const float* a1 = (const float*)d_in[6];
    const float* b1 = (const float*)d_in[7];
    const float* a3 = (const float*)d_in[8];
    const float* b3 = (const float*)d_in[9];
    const float* a2 = (const float*)d_in[10];
    const float* b2 = (const float*)d_in[11];
    float* out = (float*)d_out;

    // workspace layout (~52 MB), fp32 region first (all sizes 16B multiples)
    float* t     = (float*)d_ws;                          // 512*1024
    float* downP = t + (size_t)TT * DD;                   // 4*1024*1024
    float* s1    = downP + (size_t)4 * TT * KKSEL * DD;   // 1024*16
    float* s3    = s1 + (size_t)TT * KKSEL * RR;          // 1024*16
    float* s2    = s3 + (size_t)TT * KKSEL * RR;          // 1024*16
    float* topw  = s2 + (size_t)TT * KKSEL * RR;          // 1024
    int*   topi  = (int*)(topw + TT * KKSEL);             // 1024
    u16*   tb    = (u16*)(topi + TT * KKSEL);             // 512*1024
    u16*   w1b   = tb + (size_t)TT * DD;                  // 4096*1024
    u16*   w3b   = w1b + (size_t)FF * DD;
    u16*   w2b   = w3b + (size_t)FF * DD;
    u16*   actb  = w2b + (size_t)DD * FF;                 // 1024*4096

    f2b_k<<<2048, 256, 0, stream>>>(w1, w1b, FF * DD);
    f2b_k<<<2048, 256, 0, stream>>>(w3, w3b, FF * DD);
    f2b_k<<<2048, 256, 0, stream>>>(w2, w2b, DD * FF);
    rmsnorm_k<<<TT, 256, 0, stream>>>(x, nw, t, tb);
    router_k<<<TT, 64, 0, stream>>>(t, gw, topw, topi);
    s13_k<<<TT, 256, 0, stream>>>(t, a1, a3, topi, s1, s3);
    gemm1_fused_k<<<dim3(FF / 64, TT / 128), 256, 0, stream>>>(
        tb, w1b, w3b, b1, b3, s1, s3, topi, actb);
    s2_k<<<TT * KKSEL, 256, 0, stream>>>(actb, a2, topi, s2);
    gemm_bf16_k<<<dim3(DD / 128, (TT * KKSEL) / 128, 4), 256, 0, stream>>>(
        actb, w2b, downP, TT * KKSEL, DD, FF);
    combine_k<<<TT, 256, 0, stream>>>(downP, s2, b2, topw, topi, out);
}

// Round 4
// 149.047 us; speedup vs baseline: 3.1664x; 1.0768x over previous
//
#include <hip/hip_runtime.h>
#include <hip/hip_bf16.h>
#include <math.h>

// Problem constants (B=1)
#define TT 512      // tokens = B*S
#define DD 1024     // model dim
#define FF 4096     // ffn dim
#define EE 8        // experts
#define RR 16       // lora rank
#define KKSEL 2     // top-k
#define SCALING 2.0f
#define EPSV 1e-6f
#define DFC 128     // delta kernel f-chunk

typedef unsigned short u16;
typedef short bhalf8 __attribute__((ext_vector_type(8)));
typedef float floatx4 __attribute__((ext_vector_type(4)));

__device__ __forceinline__ u16 f2b(float f) {
    unsigned x = __builtin_bit_cast(unsigned, f);
    unsigned r = (x + 0x7fffu + ((x >> 16) & 1u)) >> 16;
    return (u16)r;
}
__device__ __forceinline__ float b2f(u16 b) {
    unsigned x = ((unsigned)b) << 16;
    return __builtin_bit_cast(float, x);
}

__device__ __forceinline__ void gl_lds16(const void* g, void* l) {
    __builtin_amdgcn_global_load_lds(
        (const __attribute__((address_space(1))) void*)g,
        (__attribute__((address_space(3))) void*)l, 16, 0, 0);
}

// ---------------- fp32 -> bf16 convert ----------------
__global__ __launch_bounds__(256) void f2b_k(const float* __restrict__ in,
                                             u16* __restrict__ out, int n) {
    int i = (blockIdx.x * 256 + threadIdx.x) * 4;
    int stride = gridDim.x * 256 * 4;
    for (; i < n; i += stride) {
        float4 v = *(const float4*)(in + i);
        ushort4 o = { f2b(v.x), f2b(v.y), f2b(v.z), f2b(v.w) };
        *(ushort4*)(out + i) = o;
    }
}

// ---------------- RMSNorm: x[T,D] -> t fp32 + bf16 ----------------
__global__ __launch_bounds__(256) void rmsnorm_k(const float* __restrict__ x,
                                                 const float* __restrict__ nw,
                                                 float* __restrict__ t,
                                                 u16* __restrict__ tb) {
    int tok = blockIdx.x;
    const float* xr = x + (size_t)tok * DD;
    float ss = 0.f;
    for (int d = threadIdx.x; d < DD; d += 256) { float v = xr[d]; ss += v * v; }
    __shared__ float red[4];
    #pragma unroll
    for (int o = 32; o > 0; o >>= 1) ss += __shfl_down(ss, o);
    int wave = threadIdx.x >> 6, lane = threadIdx.x & 63;
    if (lane == 0) red[wave] = ss;
    __syncthreads();
    if (threadIdx.x == 0) {
        float s = red[0] + red[1] + red[2] + red[3];
        red[0] = rsqrtf(s * (1.0f / DD) + EPSV);
    }
    __syncthreads();
    float rs = red[0];
    for (int d = threadIdx.x; d < DD; d += 256) {
        float v = xr[d] * rs * nw[d];
        t[(size_t)tok * DD + d] = v;
        tb[(size_t)tok * DD + d] = f2b(v);
    }
}

// ---------------- Router ----------------
__global__ __launch_bounds__(64) void router_k(const float* __restrict__ t,
                                               const float* __restrict__ gw,
                                               float* __restrict__ topw,
                                               int* __restrict__ topi) {
    int tok = blockIdx.x;
    int lane = threadIdx.x;
    const float* tr = t + (size_t)tok * DD;
    float acc[EE];
    #pragma unroll
    for (int e = 0; e < EE; e++) acc[e] = 0.f;
    for (int d = lane; d < DD; d += 64) {
        float tv = tr[d];
        #pragma unroll
        for (int e = 0; e < EE; e++) acc[e] = fmaf(tv, gw[(size_t)e * DD + d], acc[e]);
    }
    #pragma unroll
    for (int e = 0; e < EE; e++) {
        #pragma unroll
        for (int o = 32; o > 0; o >>= 1) acc[e] += __shfl_down(acc[e], o);
    }
    if (lane == 0) {
        float m = acc[0];
        #pragma unroll
        for (int e = 1; e < EE; e++) m = fmaxf(m, acc[e]);
        float p[EE];
        #pragma unroll
        for (int e = 0; e < EE; e++) p[e] = expf(acc[e] - m);
        int i0 = 0; float v0 = p[0];
        for (int e = 1; e < EE; e++) if (p[e] > v0) { v0 = p[e]; i0 = e; }
        int i1 = -1; float v1 = -1.f;
        for (int e = 0; e < EE; e++) { if (e == i0) continue; if (p[e] > v1) { v1 = p[e]; i1 = e; } }
        float inv = 1.f / (v0 + v1);
        topi[tok * KKSEL + 0] = i0;
        topi[tok * KKSEL + 1] = i1;
        topw[tok * KKSEL + 0] = v0 * inv;
        topw[tok * KKSEL + 1] = v1 * inv;
    }
}

// ---------------- bucket slots by expert ----------------
__global__ __launch_bounds__(256) void build_lists_k(const int* __restrict__ topi,
                                                     int* __restrict__ lists,
                                                     int* __restrict__ counts) {
    __shared__ int cnt[EE];
    int tid = threadIdx.x;
    if (tid < EE) cnt[tid] = 0;
    __syncthreads();
    for (int s = tid; s < TT * KKSEL; s += 256) atomicAdd(&cnt[topi[s]], 1);
    __syncthreads();
    if (tid < EE) { counts[tid] = cnt[tid]; cnt[tid] = 0; }
    __syncthreads();
    for (int s = tid; s < TT * KKSEL; s += 256) {
        int e = topi[s];
        int p = atomicAdd(&cnt[e], 1);
        lists[e * 1024 + p] = s;
    }
}

// ---------------- s1/s3: s[slot,r] = SCALING * t[tok,:] . a[e,r,:] ----------------
__global__ __launch_bounds__(256) void s13_k(const float* __restrict__ t,
                                             const float* __restrict__ a1,
                                             const float* __restrict__ a3,
                                             const int* __restrict__ topi,
                                             float* __restrict__ s1,
                                             float* __restrict__ s3) {
    int tok = blockIdx.x;
    int w = threadIdx.x >> 6, lane = threadIdx.x & 63;
    int slot = tok * 2 + (w >> 1);
    int e = topi[slot];
    const float* ap = (w & 1) ? a3 : a1;
    float* sp = (w & 1) ? s3 : s1;
    const float* tr = t + (size_t)tok * DD;
    float tv[16];
    #pragma unroll
    for (int i = 0; i < 16; i++) tv[i] = tr[lane + 64 * i];
    const float* ab = ap + (size_t)e * RR * DD;
    #pragma unroll
    for (int r = 0; r < RR; r++) {
        const float* ar = ab + (size_t)r * DD;
        float c = 0.f;
        #pragma unroll
        for (int i = 0; i < 16; i++) c = fmaf(tv[i], ar[lane + 64 * i], c);
        #pragma unroll
        for (int o = 32; o > 0; o >>= 1) c += __shfl_down(c, o);
        if (lane == 0) sp[slot * RR + r] = SCALING * c;
    }
}

// ---------------- expert-major LoRA-up delta: d[slot,f] = s[slot,:] . b[e,f,:] (bf16 out) --
// grid (FF/DFC, EE), 256 threads: tid>>7 = tensor (0:d1, 1:d3), tid&127 = f within chunk.
__global__ __launch_bounds__(256) void delta_k(const float* __restrict__ b1,
                                               const float* __restrict__ b3,
                                               const float* __restrict__ s1,
                                               const float* __restrict__ s3,
                                               const int* __restrict__ lists,
                                               const int* __restrict__ counts,
                                               u16* __restrict__ d1,
                                               u16* __restrict__ d3) {
    int e = blockIdx.y, f0 = blockIdx.x * DFC;
    __shared__ float bL[2][16 * 132];     // [tensor][r*132 + f], padded stride
    __shared__ float sG[2][32 * 16];      // [tensor][slot_local*16 + r]
    int tid = threadIdx.x;
    int ten = tid >> 7, f = tid & 127;
    // transpose-load b chunk: src b[(e*FF+f0+fi)*RR + r] -> bL[ten][r*132 + fi]
    {
        const float* bsrc1 = b1 + ((size_t)e * FF + f0) * RR;
        const float* bsrc3 = b3 + ((size_t)e * FF + f0) * RR;
        for (int i = tid; i < DFC * 16; i += 256) {
            int fi = i >> 4, r = i & 15;
            bL[0][r * 132 + fi] = bsrc1[i];
            bL[1][r * 132 + fi] = bsrc3[i];
        }
    }
    int n = counts[e];
    const int* lp = lists + e * 1024;
    const float* ssrc = ten ? s3 : s1;
    u16* dst = ten ? d3 : d1;
    for (int g = 0; g < n; g += 32) {
        int gn = min(32, n - g);
        __syncthreads();   // bL ready (1st iter) / sG no longer in use (later iters)
        int sl_l = (tid & 127) >> 2, q = tid & 3;
        if (sl_l < gn) {
            int slot = lp[g + sl_l];
            *(float4*)&sG[ten][sl_l * 16 + q * 4] = *(const float4*)&ssrc[slot * RR + q * 4];
        }
        __syncthreads();
        for (int ii = 0; ii < gn; ii++) {
            int slot = lp[g + ii];
            const float* sp = &sG[ten][ii * 16];
            float dv = 0.f;
            #pragma unroll
            for (int r = 0; r < RR; r++) dv = fmaf(sp[r], bL[ten][r * 132 + f], dv);
            dst[(size_t)slot * FF + f0 + f] = f2b(dv);
        }
    }
}

// ---------------- fused: base GEMMs (t@w1^T, t@w3^T) + delta add + SwiGLU -> actb bf16 ----
// Tile: 128 tokens x 64 f cols, BK=32. 256 threads = 4 waves (2x2), wave tile 64x32.
__global__ __launch_bounds__(256) void gemm1_fused_k(const u16* __restrict__ tb,
                                                     const u16* __restrict__ w1b,
                                                     const u16* __restrict__ w3b,
                                                     const u16* __restrict__ d1,
                                                     const u16* __restrict__ d3,
                                                     u16* __restrict__ actb) {
    __shared__ u16 As[128 * 32];
    __shared__ u16 B1s[64 * 32];
    __shared__ u16 B3s[64 * 32];
    int tid = threadIdx.x;
    int w = tid >> 6, lane = tid & 63;
    int wr = w >> 1, wc = w & 1;
    int lr = lane & 15, ks = lane >> 4;
    int m0 = blockIdx.y * 128, n0 = blockIdx.x * 64;

    int flat = tid * 16;
    int row = flat >> 6;     // 0..63
    int inb = flat & 63;
    const size_t rb = (size_t)DD * 2;  // K = DD, row bytes
    const char* Ap  = (const char*)tb  + (size_t)(m0 + row) * rb + inb;
    const char* Ap2 = Ap + 64 * rb;
    const char* B1p = (const char*)w1b + (size_t)(n0 + row) * rb + inb;
    const char* B3p = (const char*)w3b + (size_t)(n0 + row) * rb + inb;
    u16* AsW = As + w * 512;
    u16* B1W = B1s + w * 512;
    u16* B3W = B3s + w * 512;

    floatx4 zero4 = {0.f, 0.f, 0.f, 0.f};
    floatx4 acc1[4][2], acc3[4][2];
    #pragma unroll
    for (int i = 0; i < 4; i++)
        #pragma unroll
        for (int j = 0; j < 2; j++) { acc1[i][j] = zero4; acc3[i][j] = zero4; }

    for (int k0 = 0; k0 < DD; k0 += 32) {
        size_t kb = (size_t)k0 * 2;
        gl_lds16(Ap + kb, AsW);
        gl_lds16(Ap2 + kb, AsW + 2048);
        gl_lds16(B1p + kb, B1W);
        gl_lds16(B3p + kb, B3W);
        __syncthreads();
        bhalf8 af[4], bg1[2], bg3[2];
        #pragma unroll
        for (int i = 0; i < 4; i++)
            af[i] = *(const bhalf8*)&As[(wr * 64 + i * 16 + lr) * 32 + ks * 8];
        #pragma unroll
        for (int j = 0; j < 2; j++) {
            bg1[j] = *(const bhalf8*)&B1s[(wc * 32 + j * 16 + lr) * 32 + ks * 8];
            bg3[j] = *(const bhalf8*)&B3s[(wc * 32 + j * 16 + lr) * 32 + ks * 8];
        }
        #pragma unroll
        for (int i = 0; i < 4; i++)
            #pragma unroll
            for (int j = 0; j < 2; j++) {
                acc1[i][j] = __builtin_amdgcn_mfma_f32_16x16x32_bf16(af[i], bg1[j], acc1[i][j], 0, 0, 0);
                acc3[i][j] = __builtin_amdgcn_mfma_f32_16x16x32_bf16(af[i], bg3[j], acc3[i][j], 0, 0, 0);
            }
        __syncthreads();
    }

    // epilogue: h = base + delta ; act = silu(h1)*h3 -> bf16
    int crow = (lane >> 4) * 4;
    #pragma unroll
    for (int j = 0; j < 2; j++) {
        int col = n0 + wc * 32 + j * 16 + lr;
        #pragma unroll
        for (int i = 0; i < 4; i++) {
            #pragma unroll
            for (int m = 0; m < 4; m++) {
                int rowl = wr * 64 + i * 16 + crow + m;
                int tok = m0 + rowl;
                #pragma unroll
                for (int k = 0; k < KKSEL; k++) {
                    size_t off = (size_t)(tok * 2 + k) * FF + col;
                    float h1 = acc1[i][j][m] + b2f(d1[off]);
                    float h3 = acc3[i][j][m] + b2f(d3[off]);
                    float sig = 1.f / (1.f + expf(-h1));
                    actb[off] = f2b(h1 * sig * h3);
                }
            }
        }
    }
}

// ---------------- s2[slot,r] = SCALING * act[slot,:] . a2[e,r,:]  (bf16 act) --------
__global__ __launch_bounds__(256) void s2_k(const u16* __restrict__ actb,
                                            const float* __restrict__ a2,
                                            const int* __restrict__ topi,
                                            float* __restrict__ s2) {
    int slot = blockIdx.x;
    int e = topi[slot];
    const u16* ar = actb + (size_t)slot * FF;
    int wave = threadIdx.x >> 6, lane = threadIdx.x & 63;
    float av[64];
    #pragma unroll
    for (int i = 0; i < 16; i++) {
        ushort4 u = *(const ushort4*)(ar + lane * 4 + 256 * i);
        av[i * 4 + 0] = b2f(u.x); av[i * 4 + 1] = b2f(u.y);
        av[i * 4 + 2] = b2f(u.z); av[i * 4 + 3] = b2f(u.w);
    }
    #pragma unroll
    for (int rr = 0; rr < 4; rr++) {
        int r = wave * 4 + rr;
        const float* a2p = a2 + ((size_t)e * RR + r) * FF;
        float c = 0.f;
        #pragma unroll
        for (int i = 0; i < 16; i++) {
            float4 w4 = *(const float4*)(a2p + lane * 4 + 256 * i);
            c = fmaf(av[i * 4 + 0], w4.x, c);
            c = fmaf(av[i * 4 + 1], w4.y, c);
            c = fmaf(av[i * 4 + 2], w4.z, c);
            c = fmaf(av[i * 4 + 3], w4.w, c);
        }
        #pragma unroll
        for (int o = 32; o > 0; o >>= 1) c += __shfl_down(c, o);
        if (lane == 0) s2[slot * RR + r] = SCALING * c;
    }
}

// ---------------- bf16 MFMA NT GEMM, split-K (down proj) ----------------
__global__ __launch_bounds__(256) void gemm_bf16_k(const u16* __restrict__ A,
                                                   const u16* __restrict__ B,
                                                   float* __restrict__ C0,
                                                   int M, int N, int K) {
    __shared__ u16 As[128 * 32];
    __shared__ u16 Bs[128 * 32];
    int tid = threadIdx.x;
    int w = tid >> 6, lane = tid & 63;
    int wr = w >> 1, wc = w & 1;
    int lr = lane & 15, ks = lane >> 4;
    int z = blockIdx.z;
    float* C = C0 + (size_t)z * M * N;
    int kc = K >> 2, k0s = z * kc, k0e = k0s + kc;
    int m0 = blockIdx.y * 128, n0 = blockIdx.x * 128;

    int flat = tid * 16;
    int row = flat >> 6;
    int inb = flat & 63;
    size_t rb = (size_t)K * 2;
    const char* Ab  = (const char*)A + (size_t)(m0 + row) * rb + inb;
    const char* Ab2 = Ab + 64 * rb;
    const char* Bb  = (const char*)B + (size_t)(n0 + row) * rb + inb;
    const char* Bb2 = Bb + 64 * rb;
    u16* AsW = As + w * 512;
    u16* BsW = Bs + w * 512;

    floatx4 zero4 = {0.f, 0.f, 0.f, 0.f};
    floatx4 acc[4][4];
    #pragma unroll
    for (int i = 0; i < 4; i++)
        #pragma unroll
        for (int j = 0; j < 4; j++) acc[i][j] = zero4;

    for (int k0 = k0s; k0 < k0e; k0 += 32) {
        size_t kb = (size_t)k0 * 2;
        gl_lds16(Ab + kb, AsW);
        gl_lds16(Ab2 + kb, AsW + 2048);
        gl_lds16(Bb + kb, BsW);
        gl_lds16(Bb2 + kb, BsW + 2048);
        __syncthreads();
        bhalf8 af[4], bg[4];
        #pragma unroll
        for (int i = 0; i < 4; i++) {
            af[i] = *(const bhalf8*)&As[(wr * 64 + i * 16 + lr) * 32 + ks * 8];
            bg[i] = *(const bhalf8*)&Bs[(wc * 64 + i * 16 + lr) * 32 + ks * 8];
        }
        #pragma unroll
        for (int i = 0; i < 4; i++)
            #pragma unroll
            for (int j = 0; j < 4; j++)
                acc[i][j] = __builtin_amdgcn_mfma_f32_16x16x32_bf16(af[i], bg[j], acc[i][j], 0, 0, 0);
        __syncthreads();
    }

    int crow = (lane >> 4) * 4;
    #pragma unroll
    for (int i = 0; i < 4; i++) {
        #pragma unroll
        for (int j = 0; j < 4; j++) {
            float* Cp = C + (size_t)(m0 + wr * 64 + i * 16 + crow) * N + (n0 + wc * 64 + j * 16 + lr);
            Cp[0]           = acc[i][j][0];
            Cp[(size_t)N]   = acc[i][j][1];
            Cp[(size_t)2*N] = acc[i][j][2];
            Cp[(size_t)3*N] = acc[i][j][3];
        }
    }
}

// ---------------- combine: split-K partials + LoRA-down + expert weights ----------------
__global__ __launch_bounds__(256) void combine_k(const float* __restrict__ downP,
                                                 const float* __restrict__ s2,
                                                 const float* __restrict__ b2,
                                                 const float* __restrict__ topw,
                                                 const int* __restrict__ topi,
                                                 float* __restrict__ out) {
    int tok = blockIdx.x;
    for (int d = threadIdx.x; d < DD; d += 256) {
        float o = 0.f;
        #pragma unroll
        for (int k = 0; k < KKSEL; k++) {
            int slot = tok * KKSEL + k;
            int e = topi[slot];
            float w = topw[slot];
            float v = 0.f;
            #pragma unroll
            for (int zz = 0; zz < 4; zz++)
                v += downP[(size_t)zz * (TT * KKSEL) * DD + (size_t)slot * DD + d];
            const float* b2p = b2 + ((size_t)e * DD + d) * RR;
            const float* s2p = s2 + slot * RR;
            float l = 0.f;
            #pragma unroll
            for (int r = 0; r < RR; r++) l = fmaf(s2p[r], b2p[r], l);
            o += w * (v + l);
        }
        out[(size_t)tok * DD + d] = o;
    }
}

extern "C" void kernel_launch(void* const* d_in, const int* in_sizes, int n_in,
                              void* d_out, int out_size, void* d_ws, size_t ws_size,
                              hipStream_t stream) {
    const float* x  = (const float*)d_in[0];
    const float* nw = (const float*)d_in[1];
    const float* w1 = (const float*)d_in[2];
    const float* w3 = (const float*)d_in[3];
    const float* w2 = (const float*)d_in[4];
    const float* gw = (const float*)d_in[5];
    const float* a1 = (const float*)d_in[6];
    const float* b1 = (const float*)d_in[7];
    const float* a3 = (const float*)d_in[8];
    const float* b3 = (const float*)d_in[9];
    const float* a2 = (const float*)d_in[10];
    const float* b2 = (const float*)d_in[11];
    float* out = (float*)d_out;

    // workspace layout (~68 MB), all chunks 16B-aligned
    float* t     = (float*)d_ws;                          // 512*1024
    float* downP = t + (size_t)TT * DD;                   // 4*1024*1024
    float* s1    = downP + (size_t)4 * TT * KKSEL * DD;   // 1024*16
    float* s3    = s1 + (size_t)TT * KKSEL * RR;
    float* s2    = s3 + (size_t)TT * KKSEL * RR;
    float* topw  = s2 + (size_t)TT * KKSEL * RR;          // 1024
    int*   topi  = (int*)(topw + TT * KKSEL);             // 1024
    int*   lists = topi + TT * KKSEL;                     // 8*1024
    int*   counts= lists + EE * 1024;                     // 16 (padded)
    u16*   tb    = (u16*)(counts + 16);                   // 512*1024
    u16*   w1b   = tb + (size_t)TT * DD;                  // 4096*1024
    u16*   w3b   = w1b + (size_t)FF * DD;
    u16*   w2b   = w3b + (size_t)FF * DD;
    u16*   actb  = w2b + (size_t)DD * FF;                 // 1024*4096
    u16*   d1b   = actb + (size_t)TT * KKSEL * FF;        // 1024*4096
    u16*   d3b   = d1b + (size_t)TT * KKSEL * FF;

    f2b_k<<<2048, 256, 0, stream>>>(w1, w1b, FF * DD);
    f2b_k<<<2048, 256, 0, stream>>>(w3, w3b, FF * DD);
    f2b_k<<<2048, 256, 0, stream>>>(w2, w2b, DD * FF);
    rmsnorm_k<<<TT, 256, 0, stream>>>(x, nw, t, tb);
    router_k<<<TT, 64, 0, stream>>>(t, gw, topw, topi);
    build_lists_k<<<1, 256, 0, stream>>>(topi, lists, counts);
    s13_k<<<TT, 256, 0, stream>>>(t, a1, a3, topi, s1, s3);
    delta_k<<<dim3(FF / DFC, EE), 256, 0, stream>>>(b1, b3, s1, s3, lists, counts, d1b, d3b);
    gemm1_fused_k<<<dim3(FF / 64, TT / 128), 256, 0, stream>>>(
        tb, w1b, w3b, d1b, d3b, actb);
    s2_k<<<TT * KKSEL, 256, 0, stream>>>(actb, a2, topi, s2);
    gemm_bf16_k<<<dim3(DD / 128, (TT * KKSEL) / 128, 4), 256, 0, stream>>>(
        actb, w2b, downP, TT * KKSEL, DD, FF);
    combine_k<<<TT, 256, 0, stream>>>(downP, s2, b2, topw, topi, out);
}

// Round 5
// 140.290 us; speedup vs baseline: 3.3640x; 1.0624x over previous
//
#include <hip/hip_runtime.h>
#include <hip/hip_bf16.h>
#include <math.h>

// Problem constants (B=1)
#define TT 512      // tokens = B*S
#define DD 1024     // model dim
#define FF 4096     // ffn dim
#define EE 8        // experts
#define RR 16       // lora rank
#define KKSEL 2     // top-k
#define SCALING 2.0f
#define EPSV 1e-6f
#define DFC 128     // delta kernel f-chunk

typedef unsigned short u16;
typedef short bhalf8 __attribute__((ext_vector_type(8)));
typedef float floatx4 __attribute__((ext_vector_type(4)));
typedef unsigned short u16x8 __attribute__((ext_vector_type(8)));

__device__ __forceinline__ u16 f2b(float f) {
    unsigned x = __builtin_bit_cast(unsigned, f);
    unsigned r = (x + 0x7fffu + ((x >> 16) & 1u)) >> 16;
    return (u16)r;
}
__device__ __forceinline__ float b2f(u16 b) {
    unsigned x = ((unsigned)b) << 16;
    return __builtin_bit_cast(float, x);
}

__device__ __forceinline__ void gl_lds16(const void* g, void* l) {
    __builtin_amdgcn_global_load_lds(
        (const __attribute__((address_space(1))) void*)g,
        (__attribute__((address_space(3))) void*)l, 16, 0, 0);
}

// ---------------- fp32 -> bf16 convert ----------------
__global__ __launch_bounds__(256) void f2b_k(const float* __restrict__ in,
                                             u16* __restrict__ out, int n) {
    int i = (blockIdx.x * 256 + threadIdx.x) * 4;
    int stride = gridDim.x * 256 * 4;
    for (; i < n; i += stride) {
        float4 v = *(const float4*)(in + i);
        ushort4 o = { f2b(v.x), f2b(v.y), f2b(v.z), f2b(v.w) };
        *(ushort4*)(out + i) = o;
    }
}

// ---------------- RMSNorm: x[T,D] -> t fp32 + bf16 ----------------
__global__ __launch_bounds__(256) void rmsnorm_k(const float* __restrict__ x,
                                                 const float* __restrict__ nw,
                                                 float* __restrict__ t,
                                                 u16* __restrict__ tb) {
    int tok = blockIdx.x;
    const float* xr = x + (size_t)tok * DD;
    float ss = 0.f;
    for (int d = threadIdx.x; d < DD; d += 256) { float v = xr[d]; ss += v * v; }
    __shared__ float red[4];
    #pragma unroll
    for (int o = 32; o > 0; o >>= 1) ss += __shfl_down(ss, o);
    int wave = threadIdx.x >> 6, lane = threadIdx.x & 63;
    if (lane == 0) red[wave] = ss;
    __syncthreads();
    if (threadIdx.x == 0) {
        float s = red[0] + red[1] + red[2] + red[3];
        red[0] = rsqrtf(s * (1.0f / DD) + EPSV);
    }
    __syncthreads();
    float rs = red[0];
    for (int d = threadIdx.x; d < DD; d += 256) {
        float v = xr[d] * rs * nw[d];
        t[(size_t)tok * DD + d] = v;
        tb[(size_t)tok * DD + d] = f2b(v);
    }
}

// ---------------- Router ----------------
__global__ __launch_bounds__(64) void router_k(const float* __restrict__ t,
                                               const float* __restrict__ gw,
                                               float* __restrict__ topw,
                                               int* __restrict__ topi) {
    int tok = blockIdx.x;
    int lane = threadIdx.x;
    const float* tr = t + (size_t)tok * DD;
    float acc[EE];
    #pragma unroll
    for (int e = 0; e < EE; e++) acc[e] = 0.f;
    for (int d = lane; d < DD; d += 64) {
        float tv = tr[d];
        #pragma unroll
        for (int e = 0; e < EE; e++) acc[e] = fmaf(tv, gw[(size_t)e * DD + d], acc[e]);
    }
    #pragma unroll
    for (int e = 0; e < EE; e++) {
        #pragma unroll
        for (int o = 32; o > 0; o >>= 1) acc[e] += __shfl_down(acc[e], o);
    }
    if (lane == 0) {
        float m = acc[0];
        #pragma unroll
        for (int e = 1; e < EE; e++) m = fmaxf(m, acc[e]);
        float p[EE];
        #pragma unroll
        for (int e = 0; e < EE; e++) p[e] = expf(acc[e] - m);
        int i0 = 0; float v0 = p[0];
        for (int e = 1; e < EE; e++) if (p[e] > v0) { v0 = p[e]; i0 = e; }
        int i1 = -1; float v1 = -1.f;
        for (int e = 0; e < EE; e++) { if (e == i0) continue; if (p[e] > v1) { v1 = p[e]; i1 = e; } }
        float inv = 1.f / (v0 + v1);
        topi[tok * KKSEL + 0] = i0;
        topi[tok * KKSEL + 1] = i1;
        topw[tok * KKSEL + 0] = v0 * inv;
        topw[tok * KKSEL + 1] = v1 * inv;
    }
}

// ---------------- bucket slots by expert ----------------
__global__ __launch_bounds__(256) void build_lists_k(const int* __restrict__ topi,
                                                     int* __restrict__ lists,
                                                     int* __restrict__ counts) {
    __shared__ int cnt[EE];
    int tid = threadIdx.x;
    if (tid < EE) cnt[tid] = 0;
    __syncthreads();
    for (int s = tid; s < TT * KKSEL; s += 256) atomicAdd(&cnt[topi[s]], 1);
    __syncthreads();
    if (tid < EE) { counts[tid] = cnt[tid]; cnt[tid] = 0; }
    __syncthreads();
    for (int s = tid; s < TT * KKSEL; s += 256) {
        int e = topi[s];
        int p = atomicAdd(&cnt[e], 1);
        lists[e * 1024 + p] = s;
    }
}

// ---------------- s1/s3: s[slot,r] = SCALING * t[tok,:] . a[e,r,:] ----------------
__global__ __launch_bounds__(256) void s13_k(const float* __restrict__ t,
                                             const float* __restrict__ a1,
                                             const float* __restrict__ a3,
                                             const int* __restrict__ topi,
                                             float* __restrict__ s1,
                                             float* __restrict__ s3) {
    int tok = blockIdx.x;
    int w = threadIdx.x >> 6, lane = threadIdx.x & 63;
    int slot = tok * 2 + (w >> 1);
    int e = topi[slot];
    const float* ap = (w & 1) ? a3 : a1;
    float* sp = (w & 1) ? s3 : s1;
    const float* tr = t + (size_t)tok * DD;
    float tv[16];
    #pragma unroll
    for (int i = 0; i < 16; i++) tv[i] = tr[lane + 64 * i];
    const float* ab = ap + (size_t)e * RR * DD;
    #pragma unroll
    for (int r = 0; r < RR; r++) {
        const float* ar = ab + (size_t)r * DD;
        float c = 0.f;
        #pragma unroll
        for (int i = 0; i < 16; i++) c = fmaf(tv[i], ar[lane + 64 * i], c);
        #pragma unroll
        for (int o = 32; o > 0; o >>= 1) c += __shfl_down(c, o);
        if (lane == 0) sp[slot * RR + r] = SCALING * c;
    }
}

// ---------------- expert-major LoRA-up delta: d[slot,f] = s[slot,:] . b[e,f,:] ----
__global__ __launch_bounds__(256) void delta_k(const float* __restrict__ b1,
                                               const float* __restrict__ b3,
                                               const float* __restrict__ s1,
                                               const float* __restrict__ s3,
                                               const int* __restrict__ lists,
                                               const int* __restrict__ counts,
                                               u16* __restrict__ d1,
                                               u16* __restrict__ d3) {
    int e = blockIdx.y, f0 = blockIdx.x * DFC;
    __shared__ float bL[2][16 * 132];
    __shared__ float sG[2][32 * 16];
    int tid = threadIdx.x;
    int ten = tid >> 7, f = tid & 127;
    {
        const float* bsrc1 = b1 + ((size_t)e * FF + f0) * RR;
        const float* bsrc3 = b3 + ((size_t)e * FF + f0) * RR;
        for (int i = tid; i < DFC * 16; i += 256) {
            int fi = i >> 4, r = i & 15;
            bL[0][r * 132 + fi] = bsrc1[i];
            bL[1][r * 132 + fi] = bsrc3[i];
        }
    }
    int n = counts[e];
    const int* lp = lists + e * 1024;
    const float* ssrc = ten ? s3 : s1;
    u16* dst = ten ? d3 : d1;
    for (int g = 0; g < n; g += 32) {
        int gn = min(32, n - g);
        __syncthreads();
        int sl_l = (tid & 127) >> 2, q = tid & 3;
        if (sl_l < gn) {
            int slot = lp[g + sl_l];
            *(float4*)&sG[ten][sl_l * 16 + q * 4] = *(const float4*)&ssrc[slot * RR + q * 4];
        }
        __syncthreads();
        for (int ii = 0; ii < gn; ii++) {
            int slot = lp[g + ii];
            const float* sp = &sG[ten][ii * 16];
            float dv = 0.f;
            #pragma unroll
            for (int r = 0; r < RR; r++) dv = fmaf(sp[r], bL[ten][r * 132 + f], dv);
            dst[(size_t)slot * FF + f0 + f] = f2b(dv);
        }
    }
}

// ---------------- generic NT GEMM, 64x128 tile, BK=32, double-buffered LDS ----------
// C[m,n] = sum_k A[m,k]*B[n,k]; A[M,K], B[N,K] bf16 (ld=K).
// SPLITK>1: blockIdx.z = K-chunk, fp32 partial planes C[z][M][N].
// BF16OUT: single full-K pass, bf16 C.
template<int SPLITK, bool BF16OUT>
__global__ __launch_bounds__(256) void gemm_nt(const u16* __restrict__ A,
                                               const u16* __restrict__ B,
                                               void* __restrict__ Cv,
                                               int M, int N, int K) {
    __shared__ u16 As[2][64 * 32];
    __shared__ u16 Bs[2][128 * 32];
    int tid = threadIdx.x;
    int w = tid >> 6, lane = tid & 63;
    int wr = w >> 1, wc = w & 1;            // wave tile: 32(M) x 64(N)
    int lr = lane & 15, ks = lane >> 4;
    int z = (SPLITK > 1) ? blockIdx.z : 0;
    int kc = K / SPLITK;
    int k0s = z * kc;
    int nk = kc / 32;
    int m0 = blockIdx.y * 64, n0 = blockIdx.x * 128;

    // staging: thread covers 16B at flat byte tid*16 within each 64-byte-row tile
    int row = tid >> 2;            // 0..63
    int inb = (tid & 3) * 16;
    size_t rb = (size_t)K * 2;
    const char* Ag  = (const char*)A + (size_t)(m0 + row) * rb + inb + (size_t)k0s * 2;
    const char* Bg  = (const char*)B + (size_t)(n0 + row) * rb + inb + (size_t)k0s * 2;
    const char* Bg2 = Bg + 64 * rb;

    floatx4 zero4 = {0.f, 0.f, 0.f, 0.f};
    floatx4 acc[2][4];
    #pragma unroll
    for (int i = 0; i < 2; i++)
        #pragma unroll
        for (int j = 0; j < 4; j++) acc[i][j] = zero4;

    auto stage = [&](int buf, int kt) {
        size_t kb = (size_t)kt * 64;   // 32 elems * 2B
        gl_lds16(Ag + kb, &As[buf][w * 512]);
        gl_lds16(Bg + kb, &Bs[buf][w * 512]);
        gl_lds16(Bg2 + kb, &Bs[buf][2048 + w * 512]);
    };
    auto compute = [&](int buf) {
        bhalf8 af[2], bf[4];
        #pragma unroll
        for (int i = 0; i < 2; i++)
            af[i] = *(const bhalf8*)&As[buf][(wr * 32 + i * 16 + lr) * 32 + ks * 8];
        #pragma unroll
        for (int j = 0; j < 4; j++)
            bf[j] = *(const bhalf8*)&Bs[buf][(wc * 64 + j * 16 + lr) * 32 + ks * 8];
        #pragma unroll
        for (int i = 0; i < 2; i++)
            #pragma unroll
            for (int j = 0; j < 4; j++)
                acc[i][j] = __builtin_amdgcn_mfma_f32_16x16x32_bf16(af[i], bf[j], acc[i][j], 0, 0, 0);
    };

    int cur = 0;
    stage(0, 0);
    for (int kt = 0; kt < nk - 1; kt++) {
        __syncthreads();               // stage(cur) complete; prev reads of buf cur done
        stage(cur ^ 1, kt + 1);        // prefetch next (overlaps compute below)
        compute(cur);
        cur ^= 1;
    }
    __syncthreads();
    compute(cur);

    int crow = (lane >> 4) * 4;
    #pragma unroll
    for (int i = 0; i < 2; i++) {
        #pragma unroll
        for (int j = 0; j < 4; j++) {
            int r0 = m0 + wr * 32 + i * 16 + crow;
            int c0 = n0 + wc * 64 + j * 16 + lr;
            if (BF16OUT) {
                u16* Cb = (u16*)Cv;
                #pragma unroll
                for (int mm = 0; mm < 4; mm++)
                    Cb[(size_t)(r0 + mm) * N + c0] = f2b(acc[i][j][mm]);
            } else {
                float* Cf = (float*)Cv + (size_t)z * M * N;
                #pragma unroll
                for (int mm = 0; mm < 4; mm++)
                    Cf[(size_t)(r0 + mm) * N + c0] = acc[i][j][mm];
            }
        }
    }
}

// ---------------- act: actb[slot,f] = silu(h1+d1) * (h3+d3) (all bf16 streams) ------
__global__ __launch_bounds__(256) void act_k(const u16* __restrict__ hb,
                                             const u16* __restrict__ d1,
                                             const u16* __restrict__ d3,
                                             u16* __restrict__ actb) {
    int slot = blockIdx.x;
    int tok = slot >> 1;
    const u16* h1p = hb + (size_t)tok * (2 * FF);
    const u16* h3p = h1p + FF;
    const u16* d1p = d1 + (size_t)slot * FF;
    const u16* d3p = d3 + (size_t)slot * FF;
    u16* ap = actb + (size_t)slot * FF;
    #pragma unroll
    for (int it = 0; it < 2; it++) {
        int f = threadIdx.x * 8 + it * 2048;
        u16x8 v1 = *(const u16x8*)(h1p + f);
        u16x8 v3 = *(const u16x8*)(h3p + f);
        u16x8 e1 = *(const u16x8*)(d1p + f);
        u16x8 e3 = *(const u16x8*)(d3p + f);
        u16x8 o;
        #pragma unroll
        for (int q = 0; q < 8; q++) {
            float h1 = b2f(v1[q]) + b2f(e1[q]);
            float h3 = b2f(v3[q]) + b2f(e3[q]);
            float sig = 1.f / (1.f + expf(-h1));
            o[q] = f2b(h1 * sig * h3);
        }
        *(u16x8*)(ap + f) = o;
    }
}

// ---------------- s2[slot,r] = SCALING * act[slot,:] . a2[e,r,:]  (bf16 act) --------
__global__ __launch_bounds__(256) void s2_k(const u16* __restrict__ actb,
                                            const float* __restrict__ a2,
                                            const int* __restrict__ topi,
                                            float* __restrict__ s2) {
    int slot = blockIdx.x;
    int e = topi[slot];
    const u16* ar = actb + (size_t)slot * FF;
    int wave = threadIdx.x >> 6, lane = threadIdx.x & 63;
    float av[64];
    #pragma unroll
    for (int i = 0; i < 16; i++) {
        ushort4 u = *(const ushort4*)(ar + lane * 4 + 256 * i);
        av[i * 4 + 0] = b2f(u.x); av[i * 4 + 1] = b2f(u.y);
        av[i * 4 + 2] = b2f(u.z); av[i * 4 + 3] = b2f(u.w);
    }
    #pragma unroll
    for (int rr = 0; rr < 4; rr++) {
        int r = wave * 4 + rr;
        const float* a2p = a2 + ((size_t)e * RR + r) * FF;
        float c = 0.f;
        #pragma unroll
        for (int i = 0; i < 16; i++) {
            float4 w4 = *(const float4*)(a2p + lane * 4 + 256 * i);
            c = fmaf(av[i * 4 + 0], w4.x, c);
            c = fmaf(av[i * 4 + 1], w4.y, c);
            c = fmaf(av[i * 4 + 2], w4.z, c);
            c = fmaf(av[i * 4 + 3], w4.w, c);
        }
        #pragma unroll
        for (int o = 32; o > 0; o >>= 1) c += __shfl_down(c, o);
        if (lane == 0) s2[slot * RR + r] = SCALING * c;
    }
}

// ---------------- combine: split-K partials + LoRA-down + expert weights ----------------
__global__ __launch_bounds__(256) void combine_k(const float* __restrict__ downP,
                                                 const float* __restrict__ s2,
                                                 const float* __restrict__ b2,
                                                 const float* __restrict__ topw,
                                                 const int* __restrict__ topi,
                                                 float* __restrict__ out) {
    int tok = blockIdx.x;
    for (int d = threadIdx.x; d < DD; d += 256) {
        float o = 0.f;
        #pragma unroll
        for (int k = 0; k < KKSEL; k++) {
            int slot = tok * KKSEL + k;
            int e = topi[slot];
            float w = topw[slot];
            float v = 0.f;
            #pragma unroll
            for (int zz = 0; zz < 4; zz++)
                v += downP[(size_t)zz * (TT * KKSEL) * DD + (size_t)slot * DD + d];
            const float* b2p = b2 + ((size_t)e * DD + d) * RR;
            const float* s2p = s2 + slot * RR;
            float l = 0.f;
            #pragma unroll
            for (int r = 0; r < RR; r++) l = fmaf(s2p[r], b2p[r], l);
            o += w * (v + l);
        }
        out[(size_t)tok * DD + d] = o;
    }
}

extern "C" void kernel_launch(void* const* d_in, const int* in_sizes, int n_in,
                              void* d_out, int out_size, void* d_ws, size_t ws_size,
                              hipStream_t stream) {
    const float* x  = (const float*)d_in[0];
    const float* nw = (const float*)d_in[1];
    const float* w1 = (const float*)d_in[2];
    const float* w3 = (const float*)d_in[3];
    const float* w2 = (const float*)d_in[4];
    const float* gw = (const float*)d_in[5];
    const float* a1 = (const float*)d_in[6];
    const float* b1 = (const float*)d_in[7];
    const float* a3 = (const float*)d_in[8];
    const float* b3 = (const float*)d_in[9];
    const float* a2 = (const float*)d_in[10];
    const float* b2 = (const float*)d_in[11];
    float* out = (float*)d_out;

    // workspace layout (~84 MB), all chunks 16B-aligned
    float* t     = (float*)d_ws;                          // 512*1024 f32
    float* downP = t + (size_t)TT * DD;                   // 4*1024*1024 f32
    float* s1    = downP + (size_t)4 * TT * KKSEL * DD;
    float* s3    = s1 + (size_t)TT * KKSEL * RR;
    float* s2    = s3 + (size_t)TT * KKSEL * RR;
    float* topw  = s2 + (size_t)TT * KKSEL * RR;
    int*   topi  = (int*)(topw + TT * KKSEL);
    int*   lists = topi + TT * KKSEL;                     // 8*1024
    int*   counts= lists + EE * 1024;                     // 16
    u16*   tb    = (u16*)(counts + 16);                   // 512*1024
    u16*   wB    = tb + (size_t)TT * DD;                  // [w1b | w3b] 8192*1024
    u16*   w2b   = wB + (size_t)2 * FF * DD;              // 1024*4096
    u16*   hb    = w2b + (size_t)DD * FF;                 // 512 * 8192 (h1|h3 per token)
    u16*   actb  = hb + (size_t)TT * 2 * FF;              // 1024*4096
    u16*   d1b   = actb + (size_t)TT * KKSEL * FF;        // 1024*4096
    u16*   d3b   = d1b + (size_t)TT * KKSEL * FF;

    f2b_k<<<2048, 256, 0, stream>>>(w1, wB, FF * DD);
    f2b_k<<<2048, 256, 0, stream>>>(w3, wB + (size_t)FF * DD, FF * DD);
    f2b_k<<<2048, 256, 0, stream>>>(w2, w2b, DD * FF);
    rmsnorm_k<<<TT, 256, 0, stream>>>(x, nw, t, tb);
    router_k<<<TT, 64, 0, stream>>>(t, gw, topw, topi);
    build_lists_k<<<1, 256, 0, stream>>>(topi, lists, counts);
    s13_k<<<TT, 256, 0, stream>>>(t, a1, a3, topi, s1, s3);
    delta_k<<<dim3(FF / DFC, EE), 256, 0, stream>>>(b1, b3, s1, s3, lists, counts, d1b, d3b);
    // h[tok, 0:4096]=t@w1^T, h[tok, 4096:8192]=t@w3^T  (flat N=8192, 512 blocks)
    gemm_nt<1, true><<<dim3(2 * FF / 128, TT / 64), 256, 0, stream>>>(
        tb, wB, hb, TT, 2 * FF, DD);
    act_k<<<TT * KKSEL, 256, 0, stream>>>(hb, d1b, d3b, actb);
    s2_k<<<TT * KKSEL, 256, 0, stream>>>(actb, a2, topi, s2);
    // down partials: split-K=4, 512 blocks
    gemm_nt<4, false><<<dim3(DD / 128, (TT * KKSEL) / 64, 4), 256, 0, stream>>>(
        actb, w2b, downP, TT * KKSEL, DD, FF);
    combine_k<<<TT, 256, 0, stream>>>(downP, s2, b2, topw, topi, out);
}